// Round 5
// baseline (310.444 us; speedup 1.0000x reference)
//
#include <hip/hip_runtime.h>
#include <math.h>

#define NDF 11
#define MAXN 35

// ---------------------------------------------------------------------------
// k_prep: one-time weight transpose/convert into workspace + BN constants.
//   lin64 [j][k] f64 (natural), linb64/n1b64/w264 f64,
//   w1t64 [o][k] f64 (transposed), nd1t/pd1t [o][k] f32 (transposed),
//   bnc = {nd_sc[64], nd_bi[64], pd_sc[64], pd_bi[64]} f32
// ---------------------------------------------------------------------------
__global__ void k_prep(const float* __restrict__ lin_w, const float* __restrict__ lin_b,
                       const float* __restrict__ nn1_w, const float* __restrict__ nn1_b,
                       const float* __restrict__ nn2_w,
                       const float* __restrict__ nd1_w, const float* __restrict__ pd1_w,
                       const float* __restrict__ nd_g, const float* __restrict__ nd_be,
                       const float* __restrict__ nd_rm, const float* __restrict__ nd_rv,
                       const float* __restrict__ pd_g, const float* __restrict__ pd_be,
                       const float* __restrict__ pd_rm, const float* __restrict__ pd_rv,
                       double* __restrict__ lin64, double* __restrict__ linb64,
                       double* __restrict__ w1t64, double* __restrict__ n1b64,
                       double* __restrict__ w264,
                       float* __restrict__ nd1t, float* __restrict__ pd1t,
                       float* __restrict__ bnc)
{
    const int i0 = blockIdx.x * 256 + threadIdx.x;   // 16 blocks -> 4096 threads
    for (int i = i0; i < 33*64; i += 4096) lin64[i] = (double)lin_w[i];
    if (i0 < 64) {
        linb64[i0] = (double)lin_b[i0];
        n1b64[i0]  = (double)nn1_b[i0];
        w264[i0]   = (double)nn2_w[i0];
        const float sc = nd_g[i0] / sqrtf(nd_rv[i0] + 1e-5f);
        bnc[i0]        = sc;
        bnc[64 + i0]   = nd_be[i0] - nd_rm[i0] * sc;
        const float sp = pd_g[i0] / sqrtf(pd_rv[i0] + 1e-5f);
        bnc[128 + i0]  = sp;
        bnc[192 + i0]  = pd_be[i0] - pd_rm[i0] * sp;
    }
    for (int i = i0; i < 64*64; i += 4096) {
        const int o = i >> 6, k = i & 63;
        const int src = k*64 + o;
        w1t64[i] = (double)nn1_w[src];
        nd1t[i]  = nd1_w[src];
        pd1t[i]  = pd1_w[src];
    }
}

// ---------------------------------------------------------------------------
// k1: phase A (f64) + num_nodes branch (f64). One thread per graph.
// NO LDS: all weight reads are wave-uniform global loads -> scalar (s_load)
// pipe, leaving the vector pipe free for f64 FMA.
// ---------------------------------------------------------------------------
__global__ __launch_bounds__(256)
void k1_hnn(const float* __restrict__ z, const float* __restrict__ tpr,
            const double* __restrict__ lin64, const double* __restrict__ linb64,
            const double* __restrict__ w1t64, const double* __restrict__ n1b64,
            const double* __restrict__ w264, const float* __restrict__ nn2_b,
            int* __restrict__ nn_int, float* __restrict__ out_nn, int B)
{
    const int g = blockIdx.x * 256 + threadIdx.x;
    if (g >= B) return;

    const float tp = tpr[g];

    double h[64];
    #pragma unroll
    for (int k = 0; k < 64; k++) h[k] = linb64[k];

    // phase A, j-outer: 64 independent accumulators
    #pragma unroll 1
    for (int j = 0; j < 33; j++) {
        const float xv = (j < 32) ? z[(size_t)g*32 + j] : tp;   // one L1 line per thread
        const double xd = (double)xv;
        const double2* row = (const double2*)(lin64 + (size_t)j*64);
        #pragma unroll
        for (int m = 0; m < 32; m++) {
            const double2 w = row[m];
            h[2*m]   = fma(xd, w.x, h[2*m]);
            h[2*m+1] = fma(xd, w.y, h[2*m+1]);
        }
    }

    // num_nodes branch: 4 accumulator chains per output
    double logit = (double)nn2_b[0];
    #pragma unroll 1
    for (int o = 0; o < 64; o++) {
        const double2* col = (const double2*)(w1t64 + (size_t)o*64);
        double a0 = n1b64[o], a1 = 0.0, a2 = 0.0, a3 = 0.0;
        #pragma unroll
        for (int m = 0; m < 16; m++) {
            const double2 wa = col[2*m];
            const double2 wb = col[2*m+1];
            a0 = fma(h[4*m+0], wa.x, a0);
            a1 = fma(h[4*m+1], wa.y, a1);
            a2 = fma(h[4*m+2], wb.x, a2);
            a3 = fma(h[4*m+3], wb.y, a3);
        }
        const double a = (a0 + a1) + (a2 + a3);
        if (a > 0.0) logit = fma(a, w264[o], logit);
    }
    const double sg = 1.0 / (1.0 + exp(-logit));
    const int n = (int)(sg * 30.0 + 5.0);   // positive -> trunc == floor

    nn_int[g] = n;
    out_nn[g] = (float)n;
}

// ---------------------------------------------------------------------------
// k2: decode heads. Recomputes h in f32; nd/pd hidden layers with transposed
// f32 weights. All weight reads wave-uniform global -> scalar pipe. No LDS.
// ---------------------------------------------------------------------------
__global__ __launch_bounds__(256)
void k2_dec(const float* __restrict__ z, const float* __restrict__ tpr,
            const float* __restrict__ lin_w, const float* __restrict__ lin_b,
            const float* __restrict__ nd1t, const float* __restrict__ nd1_b,
            const float* __restrict__ nd2_w, const float* __restrict__ nd2_b,
            const float* __restrict__ pd1t, const float* __restrict__ pd1_b,
            const float* __restrict__ pd2_w, const float* __restrict__ pd2_b,
            const float* __restrict__ bnc,
            const float* __restrict__ nsc, const float* __restrict__ nsh,
            const float* __restrict__ psc, const float* __restrict__ psh,
            float* __restrict__ nf_g, float* __restrict__ pos_g, int B)
{
    const int g = blockIdx.x * 256 + threadIdx.x;
    if (g >= B) return;

    const float tp = tpr[g];

    float hf[64];
    #pragma unroll
    for (int k = 0; k < 64; k++) hf[k] = lin_b[k];

    #pragma unroll 1
    for (int j = 0; j < 33; j++) {
        const float xv = (j < 32) ? z[(size_t)g*32 + j] : tp;
        const float4* row = (const float4*)(lin_w + (size_t)j*64);
        #pragma unroll
        for (int m = 0; m < 16; m++) {
            const float4 w = row[m];
            hf[4*m+0] = fmaf(xv, w.x, hf[4*m+0]);
            hf[4*m+1] = fmaf(xv, w.y, hf[4*m+1]);
            hf[4*m+2] = fmaf(xv, w.z, hf[4*m+2]);
            hf[4*m+3] = fmaf(xv, w.w, hf[4*m+3]);
        }
    }

    float nf[NDF];
    #pragma unroll
    for (int j = 0; j < NDF; j++) nf[j] = nd2_b[j];
    float px = pd2_b[0], py = pd2_b[1], pz = pd2_b[2];

    #pragma unroll 1
    for (int o = 0; o < 64; o++) {
        const float4* cn = (const float4*)(nd1t + (size_t)o*64);
        const float4* cp = (const float4*)(pd1t + (size_t)o*64);
        float n0 = nd1_b[o], n1 = 0.f, n2 = 0.f, n3 = 0.f;
        float p0 = pd1_b[o], p1 = 0.f, p2 = 0.f, p3 = 0.f;
        #pragma unroll
        for (int m = 0; m < 16; m++) {
            const float4 wn = cn[m];
            const float4 wp = cp[m];
            n0 = fmaf(hf[4*m+0], wn.x, n0);
            n1 = fmaf(hf[4*m+1], wn.y, n1);
            n2 = fmaf(hf[4*m+2], wn.z, n2);
            n3 = fmaf(hf[4*m+3], wn.w, n3);
            p0 = fmaf(hf[4*m+0], wp.x, p0);
            p1 = fmaf(hf[4*m+1], wp.y, p1);
            p2 = fmaf(hf[4*m+2], wp.z, p2);
            p3 = fmaf(hf[4*m+3], wp.w, p3);
        }
        float a = (n0 + n1) + (n2 + n3); a = a > 0.f ? a : 0.f;
        float b = (p0 + p1) + (p2 + p3); b = b > 0.f ? b : 0.f;
        const float tn = fmaf(a, bnc[o],       bnc[64 + o]);
        const float tq = fmaf(b, bnc[128 + o], bnc[192 + o]);
        #pragma unroll
        for (int j = 0; j < NDF; j++)
            nf[j] = fmaf(tn, nd2_w[o*NDF + j], nf[j]);
        px = fmaf(tq, pd2_w[o*3 + 0], px);
        py = fmaf(tq, pd2_w[o*3 + 1], py);
        pz = fmaf(tq, pd2_w[o*3 + 2], pz);
    }

    const float a_ns = nsc[0], a_nh = nsh[0], a_ps = psc[0], a_ph = psh[0];
    #pragma unroll
    for (int j = 0; j < NDF; j++)
        nf_g[(size_t)g*NDF + j] = fmaf(nf[j], a_ns, a_nh);
    pos_g[(size_t)g*3 + 0] = fmaf(px, a_ps, a_ph);
    pos_g[(size_t)g*3 + 1] = fmaf(py, a_ps, a_ph);
    pos_g[(size_t)g*3 + 2] = fmaf(pz, a_ps, a_ph);
}

// ---------------------------------------------------------------------------
// 3-kernel inclusive prefix sum over B elements (B = nb*256).
// ---------------------------------------------------------------------------
__global__ __launch_bounds__(256)
void k_scan1(const int* __restrict__ a, int* __restrict__ part, int* __restrict__ bsum)
{
    __shared__ int s[256];
    const int t = threadIdx.x;
    const int g = blockIdx.x * 256 + t;
    const int v = a[g];
    s[t] = v;
    __syncthreads();
    for (int d = 1; d < 256; d <<= 1) {
        const int x = s[t];
        const int add = (t >= d) ? s[t - d] : 0;
        __syncthreads();
        s[t] = x + add;
        __syncthreads();
    }
    part[g] = s[t];
    if (t == 255) bsum[blockIdx.x] = s[255];
}

__global__ void k_scan2(const int* __restrict__ bsum, int* __restrict__ boff, int nb)
{
    __shared__ int s[1024];
    const int t = threadIdx.x;     // launched with nb threads (nb = 512, pow2)
    const int v = bsum[t];
    s[t] = v;
    __syncthreads();
    for (int d = 1; d < nb; d <<= 1) {
        const int x = s[t];
        const int add = (t >= d) ? s[t - d] : 0;
        __syncthreads();
        s[t] = x + add;
        __syncthreads();
    }
    boff[t] = s[t] - v;            // exclusive
}

__global__ __launch_bounds__(256)
void k_scan3(const int* __restrict__ part, const int* __restrict__ boff, int* __restrict__ C)
{
    const int g = blockIdx.x * 256 + threadIdx.x;
    C[g] = part[g] + boff[blockIdx.x];
}

// ---------------------------------------------------------------------------
// k_expand: 2 rows/thread, rows packed in LDS, fully-coalesced float4 stores.
// Rows >= C[B-1] repeat graph B-1 (JAX total_repeat_length padding).
// ---------------------------------------------------------------------------
__global__ __launch_bounds__(256)
void k_expand(const int* __restrict__ C, const float* __restrict__ nf_g,
              const float* __restrict__ pos_g, float* __restrict__ out,
              int B, int T)
{
    __shared__ __align__(16) float s_nf[512*NDF];   // 22528 B
    __shared__ __align__(16) float s_ps[512*3];     // 6144 B
    const int t = threadIdx.x;
    const int r0 = blockIdx.x * 512 + 2*t;

    int lo = 0, hi = B;
    while (lo < hi) {
        const int m = (lo + hi) >> 1;
        if (C[m] <= r0) lo = m + 1; else hi = m;
    }
    const int i0 = lo < B ? lo : B - 1;
    const int i1 = ((r0 + 1) >= C[i0] && i0 < B - 1) ? i0 + 1 : i0;

    #pragma unroll
    for (int j = 0; j < NDF; j++) {
        s_nf[(2*t)*NDF + j]     = nf_g[(size_t)i0*NDF + j];
        s_nf[(2*t + 1)*NDF + j] = nf_g[(size_t)i1*NDF + j];
    }
    #pragma unroll
    for (int j = 0; j < 3; j++) {
        s_ps[(2*t)*3 + j]     = pos_g[(size_t)i0*3 + j];
        s_ps[(2*t + 1)*3 + j] = pos_g[(size_t)i1*3 + j];
    }
    __syncthreads();

    float4* onf = (float4*)(out + (size_t)blockIdx.x * 512 * NDF);
    const float4* snf = (const float4*)s_nf;
    #pragma unroll
    for (int q = 0; q < 6; q++) {
        const int idx = q*256 + t;
        if (idx < 512*NDF/4) onf[idx] = snf[idx];    // 1408 float4
    }
    float4* ops = (float4*)(out + (size_t)T*NDF + (size_t)blockIdx.x * 512 * 3);
    const float4* sps = (const float4*)s_ps;
    #pragma unroll
    for (int q = 0; q < 2; q++) {
        const int idx = q*256 + t;
        if (idx < 384) ops[idx] = sps[idx];          // 384 float4
    }
}

// ---------------------------------------------------------------------------
extern "C" void kernel_launch(void* const* d_in, const int* in_sizes, int n_in,
                              void* d_out, int out_size, void* d_ws, size_t ws_size,
                              hipStream_t stream)
{
    const float* z     = (const float*)d_in[0];
    const float* tpr   = (const float*)d_in[1];
    const int    B     = in_sizes[1];          // target_property length
    const int    T     = B * MAXN;

    const float* lin_w = (const float*)d_in[3];
    const float* lin_b = (const float*)d_in[4];
    const float* nn1_w = (const float*)d_in[5];
    const float* nn1_b = (const float*)d_in[6];
    const float* nn2_w = (const float*)d_in[7];
    const float* nn2_b = (const float*)d_in[8];
    const float* nd1_w = (const float*)d_in[9];
    const float* nd1_b = (const float*)d_in[10];
    const float* nd_g  = (const float*)d_in[11];
    const float* nd_be = (const float*)d_in[12];
    const float* nd_rm = (const float*)d_in[13];
    const float* nd_rv = (const float*)d_in[14];
    const float* nd2_w = (const float*)d_in[15];
    const float* nd2_b = (const float*)d_in[16];
    const float* pd1_w = (const float*)d_in[17];
    const float* pd1_b = (const float*)d_in[18];
    const float* pd_g  = (const float*)d_in[19];
    const float* pd_be = (const float*)d_in[20];
    const float* pd_rm = (const float*)d_in[21];
    const float* pd_rv = (const float*)d_in[22];
    const float* pd2_w = (const float*)d_in[23];
    const float* pd2_b = (const float*)d_in[24];
    const float* nsc   = (const float*)d_in[25];
    const float* nsh   = (const float*)d_in[26];
    const float* psc   = (const float*)d_in[27];
    const float* psh   = (const float*)d_in[28];

    float* out = (float*)d_out;

    // workspace layout (256B-aligned slices)
    char* w = (char*)d_ws;
    size_t off = 0;
    auto take = [&](size_t bytes) { void* p = w + off; off = (off + bytes + 255) & ~(size_t)255; return p; };

    double* lin64  = (double*)take(33*64*sizeof(double));
    double* linb64 = (double*)take(64*sizeof(double));
    double* w1t64  = (double*)take(64*64*sizeof(double));
    double* n1b64  = (double*)take(64*sizeof(double));
    double* w264   = (double*)take(64*sizeof(double));
    float*  nd1t   = (float*)take(64*64*sizeof(float));
    float*  pd1t   = (float*)take(64*64*sizeof(float));
    float*  bnc    = (float*)take(256*sizeof(float));
    float*  nf_g   = (float*)take((size_t)B*NDF*sizeof(float));
    float*  pos_g  = (float*)take((size_t)B*3*sizeof(float));
    int*    nn_i   = (int*)take((size_t)B*sizeof(int));
    int*    part   = (int*)take((size_t)B*sizeof(int));
    int*    bsum   = (int*)take(4096*sizeof(int));
    int*    boff   = (int*)take(4096*sizeof(int));
    int*    C      = (int*)take((size_t)B*sizeof(int));

    const int nb = B / 256;   // 512 for B=131072

    k_prep<<<16, 256, 0, stream>>>(lin_w, lin_b, nn1_w, nn1_b, nn2_w, nd1_w, pd1_w,
                                   nd_g, nd_be, nd_rm, nd_rv, pd_g, pd_be, pd_rm, pd_rv,
                                   lin64, linb64, w1t64, n1b64, w264, nd1t, pd1t, bnc);

    k1_hnn<<<nb, 256, 0, stream>>>(z, tpr, lin64, linb64, w1t64, n1b64, w264, nn2_b,
                                   nn_i, out + (size_t)T*14, B);

    k2_dec<<<nb, 256, 0, stream>>>(z, tpr, lin_w, lin_b,
                                   nd1t, nd1_b, nd2_w, nd2_b,
                                   pd1t, pd1_b, pd2_w, pd2_b, bnc,
                                   nsc, nsh, psc, psh, nf_g, pos_g, B);

    k_scan1<<<nb, 256, 0, stream>>>(nn_i, part, bsum);
    k_scan2<<<1, nb, 0, stream>>>(bsum, boff, nb);
    k_scan3<<<nb, 256, 0, stream>>>(part, boff, C);

    k_expand<<<T/512, 256, 0, stream>>>(C, nf_g, pos_g, out, B, T);

    (void)n_in; (void)out_size; (void)ws_size;
}

// Round 6
// 286.680 us; speedup vs baseline: 1.0829x; 1.0829x over previous
//
#include <hip/hip_runtime.h>
#include <math.h>

#define NDF 11
#define MAXN 35

// ---------------------------------------------------------------------------
// k_prep: transpose hidden-layer weights to [o][k] f32, precompute BN consts,
// zero the fixup counter.
// ---------------------------------------------------------------------------
__global__ void k_prep(const float* __restrict__ nn1_w,
                       const float* __restrict__ nd1_w, const float* __restrict__ pd1_w,
                       const float* __restrict__ nd_g, const float* __restrict__ nd_be,
                       const float* __restrict__ nd_rm, const float* __restrict__ nd_rv,
                       const float* __restrict__ pd_g, const float* __restrict__ pd_be,
                       const float* __restrict__ pd_rm, const float* __restrict__ pd_rv,
                       float* __restrict__ w1t, float* __restrict__ nd1t,
                       float* __restrict__ pd1t, float* __restrict__ bnc,
                       int* __restrict__ cnt)
{
    const int i0 = blockIdx.x * 256 + threadIdx.x;   // 16 blocks
    if (i0 == 0) cnt[0] = 0;
    if (i0 < 64) {
        const float sc = nd_g[i0] / sqrtf(nd_rv[i0] + 1e-5f);
        bnc[i0]        = sc;
        bnc[64 + i0]   = nd_be[i0] - nd_rm[i0] * sc;
        const float sp = pd_g[i0] / sqrtf(pd_rv[i0] + 1e-5f);
        bnc[128 + i0]  = sp;
        bnc[192 + i0]  = pd_be[i0] - pd_rm[i0] * sp;
    }
    for (int i = i0; i < 64*64; i += 4096) {
        const int o = i >> 6, k = i & 63;
        const int src = k*64 + o;
        w1t[i]  = nn1_w[src];
        nd1t[i] = nd1_w[src];
        pd1t[i] = pd1_w[src];
    }
}

// ---------------------------------------------------------------------------
// k_fused: whole network in f32, 2 graphs per thread (weight LDS reads
// amortized 2x). Flags graphs whose floor argument is within 0.02 of an
// integer for f64 re-derivation in k_fix.
// ---------------------------------------------------------------------------
__global__ __launch_bounds__(256)
void k_fused(const float* __restrict__ z, const float* __restrict__ tpr,
             const float* __restrict__ lin_w, const float* __restrict__ lin_b,
             const float* __restrict__ w1t, const float* __restrict__ nn1_b,
             const float* __restrict__ nn2_w, const float* __restrict__ nn2_b,
             const float* __restrict__ nd1t, const float* __restrict__ nd1_b,
             const float* __restrict__ nd2_w, const float* __restrict__ nd2_b,
             const float* __restrict__ pd1t, const float* __restrict__ pd1_b,
             const float* __restrict__ pd2_w, const float* __restrict__ pd2_b,
             const float* __restrict__ bnc,
             const float* __restrict__ nsc, const float* __restrict__ nsh,
             const float* __restrict__ psc, const float* __restrict__ psh,
             float* __restrict__ nf_g, float* __restrict__ pos_g,
             int* __restrict__ nn_int, float* __restrict__ out_nn,
             int* __restrict__ flagged, int* __restrict__ cnt, int B)
{
    __shared__ __align__(16) float s_lin[33*64];    // 8448 B  [j][k]
    __shared__ __align__(16) float s_w1t[64*64];    // 16 KB   [o][k]
    __shared__ __align__(16) float s_nd1t[64*64];   // 16 KB   [o][k]
    __shared__ __align__(16) float s_pd1t[64*64];   // 16 KB   [o][k]
    __shared__ float s_nd2[64*NDF], s_pd2[64*3];
    __shared__ float s_lb[64], s_n1b[64], s_w2[64], s_ndb[64], s_pdb[64];
    __shared__ float s_bnc[256];
    __shared__ float s_nd2b[NDF], s_pd2b[3];

    const int t = threadIdx.x;
    for (int i = t; i < 33*64; i += 256) s_lin[i]  = lin_w[i];
    for (int i = t; i < 64*64; i += 256) s_w1t[i]  = w1t[i];
    for (int i = t; i < 64*64; i += 256) s_nd1t[i] = nd1t[i];
    for (int i = t; i < 64*64; i += 256) s_pd1t[i] = pd1t[i];
    for (int i = t; i < 64*NDF; i += 256) s_nd2[i] = nd2_w[i];
    if (t < 64*3) s_pd2[t] = pd2_w[t];
    if (t < 64) {
        s_lb[t]  = lin_b[t];
        s_n1b[t] = nn1_b[t];
        s_w2[t]  = nn2_w[t];
        s_ndb[t] = nd1_b[t];
        s_pdb[t] = pd1_b[t];
    }
    if (t < 256) s_bnc[t] = bnc[t];
    if (t < NDF) s_nd2b[t] = nd2_b[t];
    if (t < 3)   s_pd2b[t] = pd2_b[t];
    __syncthreads();

    const int g0 = blockIdx.x * 512 + t;
    const int g1 = g0 + 256;
    if (g0 >= B) return;

    const float tpA = tpr[g0];
    const float tpB = tpr[g1];

    // ---- phase A: h = concat(z, tp) @ lin_w + lin_b (both graphs) ----
    float hA[64], hB[64];
    #pragma unroll
    for (int k = 0; k < 64; k++) { hA[k] = s_lb[k]; hB[k] = s_lb[k]; }

    #pragma unroll 1
    for (int j = 0; j < 33; j++) {
        const float xA = (j < 32) ? z[(size_t)g0*32 + j] : tpA;
        const float xB = (j < 32) ? z[(size_t)g1*32 + j] : tpB;
        const float4* row = (const float4*)(s_lin + j*64);
        #pragma unroll
        for (int m = 0; m < 16; m++) {
            const float4 w = row[m];
            hA[4*m+0] = fmaf(xA, w.x, hA[4*m+0]);
            hA[4*m+1] = fmaf(xA, w.y, hA[4*m+1]);
            hA[4*m+2] = fmaf(xA, w.z, hA[4*m+2]);
            hA[4*m+3] = fmaf(xA, w.w, hA[4*m+3]);
            hB[4*m+0] = fmaf(xB, w.x, hB[4*m+0]);
            hB[4*m+1] = fmaf(xB, w.y, hB[4*m+1]);
            hB[4*m+2] = fmaf(xB, w.z, hB[4*m+2]);
            hB[4*m+3] = fmaf(xB, w.w, hB[4*m+3]);
        }
    }

    // ---- three hidden layers + heads, single o-loop ----
    const float l0 = nn2_b[0];
    float lgA = l0, lgB = l0;
    float nfA[NDF], nfB[NDF];
    #pragma unroll
    for (int j = 0; j < NDF; j++) { nfA[j] = s_nd2b[j]; nfB[j] = s_nd2b[j]; }
    float pxA = s_pd2b[0], pyA = s_pd2b[1], pzA = s_pd2b[2];
    float pxB = s_pd2b[0], pyB = s_pd2b[1], pzB = s_pd2b[2];

    #pragma unroll 1
    for (int o = 0; o < 64; o++) {
        const float4* c1 = (const float4*)(s_w1t  + o*64);
        const float4* cn = (const float4*)(s_nd1t + o*64);
        const float4* cp = (const float4*)(s_pd1t + o*64);
        float w1A0 = s_n1b[o], w1A1 = 0.f, w1B0 = s_n1b[o], w1B1 = 0.f;
        float ndA0 = s_ndb[o], ndA1 = 0.f, ndB0 = s_ndb[o], ndB1 = 0.f;
        float pdA0 = s_pdb[o], pdA1 = 0.f, pdB0 = s_pdb[o], pdB1 = 0.f;
        #pragma unroll
        for (int m = 0; m < 16; m++) {
            const float4 w1v = c1[m];
            const float4 wnv = cn[m];
            const float4 wpv = cp[m];
            const float a0 = hA[4*m+0], a1 = hA[4*m+1], a2 = hA[4*m+2], a3 = hA[4*m+3];
            const float b0 = hB[4*m+0], b1 = hB[4*m+1], b2 = hB[4*m+2], b3 = hB[4*m+3];
            w1A0 = fmaf(a0, w1v.x, w1A0); w1A1 = fmaf(a1, w1v.y, w1A1);
            w1A0 = fmaf(a2, w1v.z, w1A0); w1A1 = fmaf(a3, w1v.w, w1A1);
            w1B0 = fmaf(b0, w1v.x, w1B0); w1B1 = fmaf(b1, w1v.y, w1B1);
            w1B0 = fmaf(b2, w1v.z, w1B0); w1B1 = fmaf(b3, w1v.w, w1B1);
            ndA0 = fmaf(a0, wnv.x, ndA0); ndA1 = fmaf(a1, wnv.y, ndA1);
            ndA0 = fmaf(a2, wnv.z, ndA0); ndA1 = fmaf(a3, wnv.w, ndA1);
            ndB0 = fmaf(b0, wnv.x, ndB0); ndB1 = fmaf(b1, wnv.y, ndB1);
            ndB0 = fmaf(b2, wnv.z, ndB0); ndB1 = fmaf(b3, wnv.w, ndB1);
            pdA0 = fmaf(a0, wpv.x, pdA0); pdA1 = fmaf(a1, wpv.y, pdA1);
            pdA0 = fmaf(a2, wpv.z, pdA0); pdA1 = fmaf(a3, wpv.w, pdA1);
            pdB0 = fmaf(b0, wpv.x, pdB0); pdB1 = fmaf(b1, wpv.y, pdB1);
            pdB0 = fmaf(b2, wpv.z, pdB0); pdB1 = fmaf(b3, wpv.w, pdB1);
        }
        const float w2o = s_w2[o];
        const float aA = w1A0 + w1A1; if (aA > 0.f) lgA = fmaf(aA, w2o, lgA);
        const float aB = w1B0 + w1B1; if (aB > 0.f) lgB = fmaf(aB, w2o, lgB);

        float rnA = ndA0 + ndA1; rnA = rnA > 0.f ? rnA : 0.f;
        float rnB = ndB0 + ndB1; rnB = rnB > 0.f ? rnB : 0.f;
        float rpA = pdA0 + pdA1; rpA = rpA > 0.f ? rpA : 0.f;
        float rpB = pdB0 + pdB1; rpB = rpB > 0.f ? rpB : 0.f;
        const float tnA = fmaf(rnA, s_bnc[o], s_bnc[64 + o]);
        const float tnB = fmaf(rnB, s_bnc[o], s_bnc[64 + o]);
        const float tqA = fmaf(rpA, s_bnc[128 + o], s_bnc[192 + o]);
        const float tqB = fmaf(rpB, s_bnc[128 + o], s_bnc[192 + o]);
        #pragma unroll
        for (int j = 0; j < NDF; j++) {
            const float w = s_nd2[o*NDF + j];
            nfA[j] = fmaf(tnA, w, nfA[j]);
            nfB[j] = fmaf(tnB, w, nfB[j]);
        }
        const float q0 = s_pd2[o*3+0], q1 = s_pd2[o*3+1], q2 = s_pd2[o*3+2];
        pxA = fmaf(tqA, q0, pxA); pyA = fmaf(tqA, q1, pyA); pzA = fmaf(tqA, q2, pzA);
        pxB = fmaf(tqB, q0, pxB); pyB = fmaf(tqB, q1, pyB); pzB = fmaf(tqB, q2, pzB);
    }

    // ---- epilogue ----
    const float a_ns = nsc[0], a_nh = nsh[0], a_ps = psc[0], a_ph = psh[0];
    #pragma unroll
    for (int j = 0; j < NDF; j++) {
        nf_g[(size_t)g0*NDF + j] = fmaf(nfA[j], a_ns, a_nh);
        nf_g[(size_t)g1*NDF + j] = fmaf(nfB[j], a_ns, a_nh);
    }
    pos_g[(size_t)g0*3+0] = fmaf(pxA, a_ps, a_ph);
    pos_g[(size_t)g0*3+1] = fmaf(pyA, a_ps, a_ph);
    pos_g[(size_t)g0*3+2] = fmaf(pzA, a_ps, a_ph);
    pos_g[(size_t)g1*3+0] = fmaf(pxB, a_ps, a_ph);
    pos_g[(size_t)g1*3+1] = fmaf(pyB, a_ps, a_ph);
    pos_g[(size_t)g1*3+2] = fmaf(pzB, a_ps, a_ph);

    const float argA = fmaf(1.f / (1.f + expf(-lgA)), 30.f, 5.f);
    const float argB = fmaf(1.f / (1.f + expf(-lgB)), 30.f, 5.f);
    const int nA = (int)argA;
    const int nB = (int)argB;
    nn_int[g0] = nA;  out_nn[g0] = (float)nA;
    nn_int[g1] = nB;  out_nn[g1] = (float)nB;
    if (fabsf(argA - rintf(argA)) < 0.02f) { const int i = atomicAdd(cnt, 1); flagged[i] = g0; }
    if (fabsf(argB - rintf(argB)) < 0.02f) { const int i = atomicAdd(cnt, 1); flagged[i] = g1; }
}

// ---------------------------------------------------------------------------
// k_fix: f64 re-derivation of num_nodes for flagged graphs. One WAVE per
// graph: lane k computes h_k (f64), shuffle-broadcast for nn1, butterfly
// reduce for the logit.
// ---------------------------------------------------------------------------
__global__ __launch_bounds__(256)
void k_fix(const float* __restrict__ z, const float* __restrict__ tpr,
           const float* __restrict__ lin_w, const float* __restrict__ lin_b,
           const float* __restrict__ nn1_w, const float* __restrict__ nn1_b,
           const float* __restrict__ nn2_w, const float* __restrict__ nn2_b,
           const int* __restrict__ flagged, const int* __restrict__ cnt,
           int* __restrict__ nn_int, float* __restrict__ out_nn)
{
    const int count = cnt[0];
    const int lane = threadIdx.x & 63;
    const int wv = (blockIdx.x * 256 + threadIdx.x) >> 6;   // 2048 waves
    const double b2 = (double)nn2_b[0];

    for (int w = wv; w < count; w += 2048) {
        const int g = flagged[w];

        // lane k computes h_k in f64
        double hk = (double)lin_b[lane];
        for (int j = 0; j < 32; j++)
            hk = fma((double)z[(size_t)g*32 + j], (double)lin_w[j*64 + lane], hk);
        hk = fma((double)tpr[g], (double)lin_w[32*64 + lane], hk);

        // lane o computes a_o = nn1_b[o] + sum_k h_k * w1[k][o]
        double a = (double)nn1_b[lane];
        for (int k = 0; k < 64; k++) {
            const double hks = __shfl(hk, k);
            a = fma(hks, (double)nn1_w[k*64 + lane], a);
        }
        double v = (a > 0.0) ? a * (double)nn2_w[lane] : 0.0;
        for (int d = 32; d > 0; d >>= 1) v += __shfl_xor(v, d);
        const double logit = v + b2;

        if (lane == 0) {
            const double sg = 1.0 / (1.0 + exp(-logit));
            const int n = (int)(sg * 30.0 + 5.0);
            nn_int[g] = n;
            out_nn[g] = (float)n;
        }
    }
}

// ---------------------------------------------------------------------------
// 3-kernel inclusive prefix sum over B elements (B = nb*256).
// ---------------------------------------------------------------------------
__global__ __launch_bounds__(256)
void k_scan1(const int* __restrict__ a, int* __restrict__ part, int* __restrict__ bsum)
{
    __shared__ int s[256];
    const int t = threadIdx.x;
    const int g = blockIdx.x * 256 + t;
    const int v = a[g];
    s[t] = v;
    __syncthreads();
    for (int d = 1; d < 256; d <<= 1) {
        const int x = s[t];
        const int add = (t >= d) ? s[t - d] : 0;
        __syncthreads();
        s[t] = x + add;
        __syncthreads();
    }
    part[g] = s[t];
    if (t == 255) bsum[blockIdx.x] = s[255];
}

__global__ void k_scan2(const int* __restrict__ bsum, int* __restrict__ boff, int nb)
{
    __shared__ int s[1024];
    const int t = threadIdx.x;     // launched with nb threads (nb = 512, pow2)
    const int v = bsum[t];
    s[t] = v;
    __syncthreads();
    for (int d = 1; d < nb; d <<= 1) {
        const int x = s[t];
        const int add = (t >= d) ? s[t - d] : 0;
        __syncthreads();
        s[t] = x + add;
        __syncthreads();
    }
    boff[t] = s[t] - v;            // exclusive
}

__global__ __launch_bounds__(256)
void k_scan3(const int* __restrict__ part, const int* __restrict__ boff, int* __restrict__ C)
{
    const int g = blockIdx.x * 256 + threadIdx.x;
    C[g] = part[g] + boff[blockIdx.x];
}

// ---------------------------------------------------------------------------
// k_expand: 2 rows/thread, rows packed in LDS, fully-coalesced float4 stores.
// Rows >= C[B-1] repeat graph B-1 (JAX total_repeat_length padding).
// ---------------------------------------------------------------------------
__global__ __launch_bounds__(256)
void k_expand(const int* __restrict__ C, const float* __restrict__ nf_g,
              const float* __restrict__ pos_g, float* __restrict__ out,
              int B, int T)
{
    __shared__ __align__(16) float s_nf[512*NDF];   // 22528 B
    __shared__ __align__(16) float s_ps[512*3];     // 6144 B
    const int t = threadIdx.x;
    const int r0 = blockIdx.x * 512 + 2*t;

    int lo = 0, hi = B;
    while (lo < hi) {
        const int m = (lo + hi) >> 1;
        if (C[m] <= r0) lo = m + 1; else hi = m;
    }
    const int i0 = lo < B ? lo : B - 1;
    const int i1 = ((r0 + 1) >= C[i0] && i0 < B - 1) ? i0 + 1 : i0;

    #pragma unroll
    for (int j = 0; j < NDF; j++) {
        s_nf[(2*t)*NDF + j]     = nf_g[(size_t)i0*NDF + j];
        s_nf[(2*t + 1)*NDF + j] = nf_g[(size_t)i1*NDF + j];
    }
    #pragma unroll
    for (int j = 0; j < 3; j++) {
        s_ps[(2*t)*3 + j]     = pos_g[(size_t)i0*3 + j];
        s_ps[(2*t + 1)*3 + j] = pos_g[(size_t)i1*3 + j];
    }
    __syncthreads();

    float4* onf = (float4*)(out + (size_t)blockIdx.x * 512 * NDF);
    const float4* snf = (const float4*)s_nf;
    #pragma unroll
    for (int q = 0; q < 6; q++) {
        const int idx = q*256 + t;
        if (idx < 512*NDF/4) onf[idx] = snf[idx];    // 1408 float4
    }
    float4* ops = (float4*)(out + (size_t)T*NDF + (size_t)blockIdx.x * 512 * 3);
    const float4* sps = (const float4*)s_ps;
    #pragma unroll
    for (int q = 0; q < 2; q++) {
        const int idx = q*256 + t;
        if (idx < 384) ops[idx] = sps[idx];          // 384 float4
    }
}

// ---------------------------------------------------------------------------
extern "C" void kernel_launch(void* const* d_in, const int* in_sizes, int n_in,
                              void* d_out, int out_size, void* d_ws, size_t ws_size,
                              hipStream_t stream)
{
    const float* z     = (const float*)d_in[0];
    const float* tpr   = (const float*)d_in[1];
    const int    B     = in_sizes[1];          // target_property length
    const int    T     = B * MAXN;

    const float* lin_w = (const float*)d_in[3];
    const float* lin_b = (const float*)d_in[4];
    const float* nn1_w = (const float*)d_in[5];
    const float* nn1_b = (const float*)d_in[6];
    const float* nn2_w = (const float*)d_in[7];
    const float* nn2_b = (const float*)d_in[8];
    const float* nd1_w = (const float*)d_in[9];
    const float* nd1_b = (const float*)d_in[10];
    const float* nd_g  = (const float*)d_in[11];
    const float* nd_be = (const float*)d_in[12];
    const float* nd_rm = (const float*)d_in[13];
    const float* nd_rv = (const float*)d_in[14];
    const float* nd2_w = (const float*)d_in[15];
    const float* nd2_b = (const float*)d_in[16];
    const float* pd1_w = (const float*)d_in[17];
    const float* pd1_b = (const float*)d_in[18];
    const float* pd_g  = (const float*)d_in[19];
    const float* pd_be = (const float*)d_in[20];
    const float* pd_rm = (const float*)d_in[21];
    const float* pd_rv = (const float*)d_in[22];
    const float* pd2_w = (const float*)d_in[23];
    const float* pd2_b = (const float*)d_in[24];
    const float* nsc   = (const float*)d_in[25];
    const float* nsh   = (const float*)d_in[26];
    const float* psc   = (const float*)d_in[27];
    const float* psh   = (const float*)d_in[28];

    float* out = (float*)d_out;

    // workspace layout (256B-aligned slices)
    char* w = (char*)d_ws;
    size_t off = 0;
    auto take = [&](size_t bytes) { void* p = w + off; off = (off + bytes + 255) & ~(size_t)255; return p; };

    float* w1t   = (float*)take(64*64*sizeof(float));
    float* nd1t  = (float*)take(64*64*sizeof(float));
    float* pd1t  = (float*)take(64*64*sizeof(float));
    float* bnc   = (float*)take(256*sizeof(float));
    int*   cnt   = (int*)take(256);
    float* nf_g  = (float*)take((size_t)B*NDF*sizeof(float));
    float* pos_g = (float*)take((size_t)B*3*sizeof(float));
    int*   nn_i  = (int*)take((size_t)B*sizeof(int));
    int*   part  = (int*)take((size_t)B*sizeof(int));
    int*   bsum  = (int*)take(4096*sizeof(int));
    int*   boff  = (int*)take(4096*sizeof(int));
    int*   C     = (int*)take((size_t)B*sizeof(int));
    int*   flagged = C;   // alias: flagged is consumed by k_fix BEFORE scan3 writes C

    const int nb = B / 256;   // 512 for B=131072

    k_prep<<<16, 256, 0, stream>>>(nn1_w, nd1_w, pd1_w,
                                   nd_g, nd_be, nd_rm, nd_rv,
                                   pd_g, pd_be, pd_rm, pd_rv,
                                   w1t, nd1t, pd1t, bnc, cnt);

    k_fused<<<B/512, 256, 0, stream>>>(z, tpr, lin_w, lin_b,
                                       w1t, nn1_b, nn2_w, nn2_b,
                                       nd1t, nd1_b, nd2_w, nd2_b,
                                       pd1t, pd1_b, pd2_w, pd2_b, bnc,
                                       nsc, nsh, psc, psh,
                                       nf_g, pos_g, nn_i, out + (size_t)T*14,
                                       flagged, cnt, B);

    k_fix<<<512, 256, 0, stream>>>(z, tpr, lin_w, lin_b, nn1_w, nn1_b, nn2_w, nn2_b,
                                   flagged, cnt, nn_i, out + (size_t)T*14);

    k_scan1<<<nb, 256, 0, stream>>>(nn_i, part, bsum);
    k_scan2<<<1, nb, 0, stream>>>(bsum, boff, nb);
    k_scan3<<<nb, 256, 0, stream>>>(part, boff, C);

    k_expand<<<T/512, 256, 0, stream>>>(C, nf_g, pos_g, out, B, T);

    (void)n_in; (void)out_size; (void)ws_size;
}